// Round 1
// baseline (204.002 us; speedup 1.0000x reference)
//
#include <hip/hip_runtime.h>

typedef __attribute__((ext_vector_type(8))) _Float16 f16x8;
typedef __attribute__((ext_vector_type(4))) float fv4;
typedef __attribute__((ext_vector_type(4))) int iv4;

#define K_IN 4096
#define N_OUT 4096
#define GRPS_PER_ROW 256 /* K_IN/16 */

// ---------------------------------------------------------------------------
// Kernel 1: xa[b][r] = sum_i x[b][i] * lora_a[r][i]   (1024 x 16 into d_ws)
// 4 threads split K per (b,r) pair; shfl reduce.
// ---------------------------------------------------------------------------
__global__ __launch_bounds__(256) void xa_kernel(const float* __restrict__ x,
                                                 const float* __restrict__ la,
                                                 float* __restrict__ xa) {
    int tid = blockIdx.x * 256 + threadIdx.x;
    int ks = tid & 3;
    int p  = tid >> 2;          // 0..16383 = b*16 + r
    int b = p >> 4, r = p & 15;
    const fv4* xp = (const fv4*)(x + (size_t)b * K_IN + ks * 1024);
    const fv4* ap = (const fv4*)(la + (size_t)r * K_IN + ks * 1024);
    float acc = 0.f;
#pragma unroll 8
    for (int i = 0; i < 256; ++i) {
        fv4 xv = xp[i], av = ap[i];
        acc += xv.x * av.x + xv.y * av.y + xv.z * av.z + xv.w * av.w;
    }
    acc += __shfl_xor(acc, 1);
    acc += __shfl_xor(acc, 2);
    if (ks == 0) xa[p] = acc;
}

// ---------------------------------------------------------------------------
// Kernel 2: fused dequant GEMM + rank-16 LoRA extra K-step.
// BM=128, BN=128, BK=64, 256 threads = 4 waves (2x2), 64x64 out per wave.
// LDS: As[2]/Bs[2] 16KB each (f16, [row][64k], 16B-granule XOR swizzle).
// ---------------------------------------------------------------------------
__global__ __launch_bounds__(256) void qlora_gemm(
        const float* __restrict__ x, const int* __restrict__ qw,
        const float* __restrict__ sc, const float* __restrict__ lb,
        const float* __restrict__ alphap, const float* __restrict__ xa,
        float* __restrict__ out)
{
    __shared__ __align__(16) char lds[65536];

    // XCD-aware decode: XCD = bid&7 gets a 4(by) x 8(bx) sub-grid.
    int bid = blockIdx.x;
    int q = bid & 7, jj = bid >> 3;
    int by = ((q & 1) << 2) | (jj & 3);   // 0..7
    int bx = ((q >> 1) << 3) | (jj >> 2); // 0..31
    int bm0 = by << 7, bn0 = bx << 7;

    int t = threadIdx.x;
    int lane = t & 63;
    int wid = t >> 6;
    int wm = (wid >> 1) & 1, wn = wid & 1;

    int srow  = t >> 1;   // 0..127: staging row (A row / B out-col)
    int shalf = t & 1;    // which 32-wide k half
    int rs = srow & 7;

    const float* aptr = x + (size_t)(bm0 + srow) * K_IN + shalf * 32;
    int gbase = (bn0 + srow) * GRPS_PER_ROW + shalf * 2;

    fv4 ar[8];
    iv4 bq[4];
    float bsc[2];

    auto LOAD = [&](int ts) {
        const float* ap = aptr + ts * 64;
#pragma unroll
        for (int i = 0; i < 8; ++i) ar[i] = *(const fv4*)(ap + i * 4);
        int g0 = gbase + (ts << 2);
#pragma unroll
        for (int j2 = 0; j2 < 2; ++j2) {
            const int* qp = qw + (size_t)(g0 + j2) * 8;
            bq[j2 * 2 + 0] = *(const iv4*)(qp);
            bq[j2 * 2 + 1] = *(const iv4*)(qp + 4);
            bsc[j2] = sc[g0 + j2];
        }
    };

    auto STORE = [&](int buf) {
        char* As = lds + buf * 16384;
        char* Bs = lds + 32768 + buf * 16384;
        // A: 32 fp32 -> f16
        union { _Float16 h[32]; iv4 v[4]; } ua;
#pragma unroll
        for (int i = 0; i < 8; ++i) {
            ua.h[i * 4 + 0] = (_Float16)ar[i].x;
            ua.h[i * 4 + 1] = (_Float16)ar[i].y;
            ua.h[i * 4 + 2] = (_Float16)ar[i].z;
            ua.h[i * 4 + 3] = (_Float16)ar[i].w;
        }
#pragma unroll
        for (int h = 0; h < 4; ++h) {
            int g = (shalf << 2) | h;
            *(iv4*)(As + srow * 128 + ((g ^ rs) << 4)) = ua.v[h];
        }
        // B: dequant 2 groups (32 weights): w = q*(2s/15) - s, lo/hi interleave
        union { _Float16 h[32]; iv4 v[4]; } ub;
#pragma unroll
        for (int j2 = 0; j2 < 2; ++j2) {
            float c0 = bsc[j2] * (2.0f / 15.0f);
            float c1 = -bsc[j2];
            int vals[8] = {bq[j2*2].x, bq[j2*2].y, bq[j2*2].z, bq[j2*2].w,
                           bq[j2*2+1].x, bq[j2*2+1].y, bq[j2*2+1].z, bq[j2*2+1].w};
#pragma unroll
            for (int e = 0; e < 8; ++e) {
                int v = vals[e];
                ub.h[j2*16 + e*2 + 0] = (_Float16)fmaf((float)(v & 15), c0, c1);
                ub.h[j2*16 + e*2 + 1] = (_Float16)fmaf((float)((v >> 4) & 15), c0, c1);
            }
        }
#pragma unroll
        for (int h = 0; h < 4; ++h) {
            int g = (shalf << 2) | h;
            *(iv4*)(Bs + srow * 128 + ((g ^ rs) << 4)) = ub.v[h];
        }
    };

    fv4 acc[4][4];
#pragma unroll
    for (int m = 0; m < 4; ++m)
#pragma unroll
        for (int n = 0; n < 4; ++n)
            acc[m][n] = fv4{0.f, 0.f, 0.f, 0.f};

    auto COMPUTE = [&](int buf) {
        char* As = lds + buf * 16384;
        char* Bs = lds + 32768 + buf * 16384;
#pragma unroll
        for (int ks2 = 0; ks2 < 2; ++ks2) {
            f16x8 a[4], b[4];
            int gk = (ks2 << 2) | (lane >> 4);
            int rl = lane & 15;
            int r7 = rl & 7;
#pragma unroll
            for (int m = 0; m < 4; ++m) {
                int row = (wm << 6) + (m << 4) + rl;
                a[m] = *(const f16x8*)(As + row * 128 + ((gk ^ r7) << 4));
            }
#pragma unroll
            for (int n = 0; n < 4; ++n) {
                int col = (wn << 6) + (n << 4) + rl;
                b[n] = *(const f16x8*)(Bs + col * 128 + ((gk ^ r7) << 4));
            }
#pragma unroll
            for (int m = 0; m < 4; ++m)
#pragma unroll
                for (int n = 0; n < 4; ++n)
                    acc[m][n] = __builtin_amdgcn_mfma_f32_16x16x32_f16(
                        a[m], b[n], acc[m][n], 0, 0, 0);
        }
    };

    LOAD(0);
    STORE(0);
    __syncthreads();
    for (int ts = 0; ts < 64; ++ts) {
        int cur = ts & 1;
        if (ts < 63) LOAD(ts + 1);   // prefetch next K-step (globals in flight)
        COMPUTE(cur);
        if (ts < 63) STORE(cur ^ 1); // write other buffer; barrier covers it
        __syncthreads();
    }

    // ---- LoRA rank-16 as one extra K-step (k=0..15 data, 16..31 zeros) ----
    {
        float al = alphap[0];
        const float* xs0 = xa + (size_t)(bm0 + srow) * 16;
        const float* ws0 = lb + (size_t)(bn0 + srow) * 16;
#pragma unroll
        for (int h = 0; h < 2; ++h) {
            int g = (shalf << 1) | h;   // granule 0..3 (k = g*8..g*8+7)
            union { _Float16 hh[8]; iv4 v; } ux, uw;
            if (g < 2) {
#pragma unroll
                for (int e = 0; e < 8; ++e) {
                    ux.hh[e] = (_Float16)xs0[g * 8 + e];
                    uw.hh[e] = (_Float16)(al * ws0[g * 8 + e]);
                }
            } else {
                ux.v = iv4{0, 0, 0, 0};
                uw.v = iv4{0, 0, 0, 0};
            }
            *(iv4*)(lds + srow * 128 + ((g ^ rs) << 4)) = ux.v;
            *(iv4*)(lds + 32768 + srow * 128 + ((g ^ rs) << 4)) = uw.v;
        }
    }
    __syncthreads();
    {
        f16x8 a[4], b[4];
        int gk = lane >> 4;
        int rl = lane & 15;
        int r7 = rl & 7;
#pragma unroll
        for (int m = 0; m < 4; ++m) {
            int row = (wm << 6) + (m << 4) + rl;
            a[m] = *(const f16x8*)(lds + row * 128 + ((gk ^ r7) << 4));
        }
#pragma unroll
        for (int n = 0; n < 4; ++n) {
            int col = (wn << 6) + (n << 4) + rl;
            b[n] = *(const f16x8*)(lds + 32768 + col * 128 + ((gk ^ r7) << 4));
        }
#pragma unroll
        for (int m = 0; m < 4; ++m)
#pragma unroll
            for (int n = 0; n < 4; ++n)
                acc[m][n] = __builtin_amdgcn_mfma_f32_16x16x32_f16(
                    a[m], b[n], acc[m][n], 0, 0, 0);
    }

    // ---- epilogue: C/D layout col=lane&15, row=(lane>>4)*4+r ----
#pragma unroll
    for (int m = 0; m < 4; ++m) {
        int row0 = bm0 + (wm << 6) + (m << 4) + ((lane >> 4) << 2);
#pragma unroll
        for (int n = 0; n < 4; ++n) {
            int col = bn0 + (wn << 6) + (n << 4) + (lane & 15);
#pragma unroll
            for (int r = 0; r < 4; ++r)
                out[(size_t)(row0 + r) * N_OUT + col] = acc[m][n][r];
        }
    }
}

extern "C" void kernel_launch(void* const* d_in, const int* in_sizes, int n_in,
                              void* d_out, int out_size, void* d_ws, size_t ws_size,
                              hipStream_t stream) {
    const float* x  = (const float*)d_in[0];
    const int*   qw = (const int*)d_in[1];
    const float* sc = (const float*)d_in[2];
    const float* la = (const float*)d_in[3];
    const float* lb = (const float*)d_in[4];
    const float* al = (const float*)d_in[5];
    float* out = (float*)d_out;
    float* xa  = (float*)d_ws;   // 1024*16 fp32 = 64 KB scratch

    xa_kernel<<<256, 256, 0, stream>>>(x, la, xa);
    qlora_gemm<<<256, 256, 0, stream>>>(x, qw, sc, lb, al, xa, out);
}

// Round 3
// 134.739 us; speedup vs baseline: 1.5141x; 1.5141x over previous
//
#include <hip/hip_runtime.h>

typedef __attribute__((ext_vector_type(2))) _Float16 h2;
typedef __attribute__((ext_vector_type(2))) __fp16 p2;   // cvt_pkrtz return type
typedef __attribute__((ext_vector_type(8))) _Float16 f16x8;
typedef __attribute__((ext_vector_type(4))) float fv4;
typedef __attribute__((ext_vector_type(4))) int iv4;
typedef __attribute__((ext_vector_type(2))) int iv2;

#define K_IN 4096
#define N_OUT 4096

// ---------------------------------------------------------------------------
// Kernel 1: xa[b][r] = sum_i x[b][i] * lora_a[r][i]
// 256 blocks x 256 thr; each wave = one b-row; 16 r x 4 k-slices per wave.
// x addresses broadcast across the 16 ranks -> x read once from HBM.
// ---------------------------------------------------------------------------
__global__ __launch_bounds__(256) void xa_kernel(const float* __restrict__ x,
                                                 const float* __restrict__ la,
                                                 float* __restrict__ xa) {
    int t = threadIdx.x;
    int bl = t >> 6;          // wave id = local b row
    int r = (t >> 2) & 15;
    int ks = t & 3;
    int b = blockIdx.x * 4 + bl;
    const fv4* xp = (const fv4*)(x + (size_t)b * K_IN + ks * 1024);
    const fv4* ap = (const fv4*)(la + (size_t)r * K_IN + ks * 1024);
    float acc = 0.f;
#pragma unroll 8
    for (int i = 0; i < 256; ++i) {
        fv4 xv = xp[i], av = ap[i];
        acc += xv.x * av.x + xv.y * av.y + xv.z * av.z + xv.w * av.w;
    }
    acc += __shfl_xor(acc, 1);
    acc += __shfl_xor(acc, 2);
    if (ks == 0) xa[b * 16 + r] = acc;
}

// ---------------------------------------------------------------------------
// Kernel 2: fused dequant GEMM + rank-16 LoRA.
// 256 blocks x 512 thr (8 waves). BM=BN=128, BK=128, 32 K-steps.
// Wave grid: (wm,wn,kg) = 2x2x2 -> each wave 64x64 tile over half of K.
// LDS 128KB: A f16 dbuf [128][256B] @0/32768, B f16 dbuf @65536/98304.
// 16B-granule XOR swizzle (g ^ (row&7)) on both tiles.
// ---------------------------------------------------------------------------
__global__ __launch_bounds__(512, 2) void qlora_gemm(
        const float* __restrict__ x, const int* __restrict__ qw,
        const float* __restrict__ sc, const float* __restrict__ lb,
        const float* __restrict__ alphap, const float* __restrict__ xa,
        float* __restrict__ out)
{
    __shared__ __align__(16) char lds[131072];

    // XCD-aware decode: XCD = bid&7 owns a 4(by) x 8(bx) sub-grid.
    int bid = blockIdx.x;
    int qd = bid & 7, jj = bid >> 3;
    int by = ((qd & 1) << 2) | (jj & 3);   // 0..7
    int bx = ((qd >> 1) << 3) | (jj >> 2); // 0..31
    int bm0 = by << 7, bn0 = bx << 7;

    int t = threadIdx.x;
    int lane = t & 63;
    int wid = t >> 6;
    int kg = wid & 1, wn = (wid >> 1) & 1, wm = wid >> 2;
    int rl = lane & 15, hq = lane >> 4;

    // ---- staging maps ----
    // A: inst i reads row (i*16 + t>>5), 4 f32 at k=(t&31)*4  (512B contig/row)
    int arow_t = t >> 5;          // 0..15
    int akc = t & 31;             // k quad
    const float* agp = x + (size_t)(bm0 + arow_t) * K_IN + akc * 4;
    // B: inst j reads col (j*32 + t>>4), 16B raw at byte (t&15)*16 of the
    // col's 256B per-step chunk (256B contig/col).
    int bcol_t = t >> 4;          // 0..31
    int bk16 = t & 15;            // granule index
    const char* bgp = (const char*)qw + (size_t)(bn0 + bcol_t) * 8192 + bk16 * 16;
    const float* sgp = sc + (size_t)(bn0 + bcol_t) * 256 + (bk16 >> 1);

    fv4 Ar[8];
    iv4 Br[4];
    float Sr[4];

    auto LOAD = [&](int ts) {
#pragma unroll
        for (int i = 0; i < 8; ++i)
            Ar[i] = *(const fv4*)(agp + (size_t)i * 16 * K_IN + ts * 128);
#pragma unroll
        for (int j = 0; j < 4; ++j) {
            Br[j] = *(const iv4*)(bgp + (size_t)j * 32 * 8192 + ts * 256);
            Sr[j] = sgp[(size_t)j * 32 * 256 + ts * 8];
        }
    };

    auto STORE = [&](int buf) {
        char* As = lds + buf * 32768;
        char* Bsp = lds + 65536 + buf * 32768;
        // A: fp32 -> f16, 8B per inst
#pragma unroll
        for (int i = 0; i < 8; ++i) {
            int row = i * 16 + arow_t;
            union { p2 h[2]; iv2 v; } u;
            u.h[0] = __builtin_amdgcn_cvt_pkrtz(Ar[i].x, Ar[i].y);
            u.h[1] = __builtin_amdgcn_cvt_pkrtz(Ar[i].z, Ar[i].w);
            int g = akc >> 1;
            *(iv2*)(As + row * 256 + ((g ^ (row & 7)) << 4) + (akc & 1) * 8) = u.v;
        }
        // B: dequant 4 cols x 8 weights via f16-bias trick
#pragma unroll
        for (int j = 0; j < 4; ++j) {
            float s = Sr[j];
            _Float16 c0h = (_Float16)(s * (2.0f / 15.0f));
            _Float16 c1h = (_Float16)(-s);
            h2 c0 = {c0h, c0h}, c1 = {c1h, c1h};
            h2 m1024 = {(_Float16)-1024.f, (_Float16)-1024.f};
            union { h2 h[4]; iv4 v; } o;
#pragma unroll
            for (int w = 0; w < 4; ++w) {
                unsigned wv = (unsigned)Br[j][w];
                unsigned qb = (wv & 15u) | ((wv & 0xF0u) << 12) | 0x64006400u;
                h2 qh;
                __builtin_memcpy(&qh, &qb, 4);
                o.h[w] = (qh + m1024) * c0 + c1;
            }
            int col = j * 32 + bcol_t;
            *(iv4*)(Bsp + col * 256 + ((bk16 ^ (col & 7)) << 4)) = o.v;
        }
    };

    fv4 acc[4][4];
#pragma unroll
    for (int m = 0; m < 4; ++m)
#pragma unroll
        for (int n = 0; n < 4; ++n)
            acc[m][n] = fv4{0.f, 0.f, 0.f, 0.f};

    auto COMPUTE = [&](int buf) {
        const char* As = lds + buf * 32768;
        const char* Bsp = lds + 65536 + buf * 32768;
#pragma unroll
        for (int ks2 = 0; ks2 < 2; ++ks2) {
            f16x8 a[4], b[4];
            int gk = kg * 8 + ks2 * 4 + hq;
#pragma unroll
            for (int m = 0; m < 4; ++m) {
                int row = wm * 64 + m * 16 + rl;
                a[m] = *(const f16x8*)(As + row * 256 + ((gk ^ (row & 7)) << 4));
            }
#pragma unroll
            for (int n = 0; n < 4; ++n) {
                int col = wn * 64 + n * 16 + rl;
                b[n] = *(const f16x8*)(Bsp + col * 256 + ((gk ^ (col & 7)) << 4));
            }
#pragma unroll
            for (int m = 0; m < 4; ++m)
#pragma unroll
                for (int n = 0; n < 4; ++n)
                    acc[m][n] = __builtin_amdgcn_mfma_f32_16x16x32_f16(
                        a[m], b[n], acc[m][n], 0, 0, 0);
        }
    };

    // ---- main loop: loads fly during compute; store after; one barrier ----
    LOAD(0);
    STORE(0);
    __syncthreads();
    for (int ts = 0; ts < 32; ++ts) {
        if (ts < 31) LOAD(ts + 1);
        COMPUTE(ts & 1);
        if (ts < 31) STORE((ts + 1) & 1);
        __syncthreads();
    }

    // ---- LoRA: one extra K-step (k=0..15 data, 16..31 zeros), kg==0 only ----
    {
        float al = alphap[0];
        int lrow = t >> 2, lg = t & 3;
        union { p2 h[4]; iv4 v; } ux, uw;
        if (lg < 2) {
            const float* xp = xa + (size_t)(bm0 + lrow) * 16 + lg * 8;
            const float* wp = lb + (size_t)(bn0 + lrow) * 16 + lg * 8;
#pragma unroll
            for (int e = 0; e < 4; ++e) {
                ux.h[e] = __builtin_amdgcn_cvt_pkrtz(xp[2 * e], xp[2 * e + 1]);
                uw.h[e] = __builtin_amdgcn_cvt_pkrtz(al * wp[2 * e], al * wp[2 * e + 1]);
            }
        } else {
            ux.v = iv4{0, 0, 0, 0};
            uw.v = iv4{0, 0, 0, 0};
        }
        *(iv4*)(lds + lrow * 256 + ((lg ^ (lrow & 7)) << 4)) = ux.v;
        *(iv4*)(lds + 65536 + lrow * 256 + ((lg ^ (lrow & 7)) << 4)) = uw.v;
    }
    __syncthreads();
    if (kg == 0) {
        f16x8 a[4], b[4];
        int gk = hq;
#pragma unroll
        for (int m = 0; m < 4; ++m) {
            int row = wm * 64 + m * 16 + rl;
            a[m] = *(const f16x8*)(lds + row * 256 + ((gk ^ (row & 7)) << 4));
        }
#pragma unroll
        for (int n = 0; n < 4; ++n) {
            int col = wn * 64 + n * 16 + rl;
            b[n] = *(const f16x8*)(lds + 65536 + col * 256 + ((gk ^ (col & 7)) << 4));
        }
#pragma unroll
        for (int m = 0; m < 4; ++m)
#pragma unroll
            for (int n = 0; n < 4; ++n)
                acc[m][n] = __builtin_amdgcn_mfma_f32_16x16x32_f16(
                    a[m], b[n], acc[m][n], 0, 0, 0);
    } else {
        // kg==1: dump partial acc to LDS for the kg==0 partner to add.
        int sm = wm * 2 + wn;
        char* exb = lds + (sm < 2 ? 32768 + sm * 16384 : 98304 + (sm - 2) * 16384);
#pragma unroll
        for (int m = 0; m < 4; ++m)
#pragma unroll
            for (int n = 0; n < 4; ++n)
                *(fv4*)(exb + (m * 4 + n) * 1024 + lane * 16) = acc[m][n];
    }
    __syncthreads();
    if (kg == 0) {
        int sm = wm * 2 + wn;
        const char* exb = lds + (sm < 2 ? 32768 + sm * 16384 : 98304 + (sm - 2) * 16384);
#pragma unroll
        for (int m = 0; m < 4; ++m) {
            int row0 = bm0 + wm * 64 + m * 16 + hq * 4;
#pragma unroll
            for (int n = 0; n < 4; ++n) {
                fv4 p = *(const fv4*)(exb + (m * 4 + n) * 1024 + lane * 16);
                fv4 v = acc[m][n];
                v.x += p.x; v.y += p.y; v.z += p.z; v.w += p.w;
                int col = bn0 + wn * 64 + n * 16 + rl;
#pragma unroll
                for (int r = 0; r < 4; ++r)
                    out[(size_t)(row0 + r) * N_OUT + col] = v[r];
            }
        }
    }
}

extern "C" void kernel_launch(void* const* d_in, const int* in_sizes, int n_in,
                              void* d_out, int out_size, void* d_ws, size_t ws_size,
                              hipStream_t stream) {
    const float* x  = (const float*)d_in[0];
    const int*   qw = (const int*)d_in[1];
    const float* sc = (const float*)d_in[2];
    const float* la = (const float*)d_in[3];
    const float* lb = (const float*)d_in[4];
    const float* al = (const float*)d_in[5];
    float* out = (float*)d_out;
    float* xa  = (float*)d_ws;   // 1024*16 fp32 = 64 KB scratch

    xa_kernel<<<256, 256, 0, stream>>>(x, la, xa);
    qlora_gemm<<<256, 512, 0, stream>>>(x, qw, sc, lb, al, xa, out);
}